// Round 11
// baseline (145.572 us; speedup 1.0000x reference)
//
#include <hip/hip_runtime.h>
#include <math.h>
#include <type_traits>

#define BB 2
#define SS 2048
#define DD 64
#define HH 12
// Q pre-scaled by 1/ln2 in qkv; exp(s-16) == exp2(s' - 16/ln2)
#define C2FIX 23.083120654223414f
#define NITEMS (64 * BB * HH)          // 1536 work items

typedef _Float16 v8h __attribute__((ext_vector_type(8)));
typedef short    v8s __attribute__((ext_vector_type(8)));
typedef float    v4f __attribute__((ext_vector_type(4)));
typedef unsigned int v2u __attribute__((ext_vector_type(2)));

__device__ __forceinline__ unsigned short f2bf(float f) {
    unsigned u = __float_as_uint(f);
    u += 0x7FFF + ((u >> 16) & 1);          // RTN-even
    return (unsigned short)(u >> 16);
}

__device__ __forceinline__ void async16(const void* g, void* l) {
    __builtin_amdgcn_global_load_lds(
        (const __attribute__((address_space(1))) unsigned int*)g,
        (__attribute__((address_space(3))) unsigned int*)l, 16, 0, 0);
}

// ---------------------------------------------------------------------------
// Kernel 0: prep. x -> x16 fp16; [Wq|Wk|Wv] -> W16 fp16 B-layout [2304][64];
// Wo -> WoT fp16 [64][768]. Also zeroes the work-stealing counter (stream
// order guarantees it's 0 before attn starts; re-executed on every replay).
// ---------------------------------------------------------------------------
__global__ __launch_bounds__(256) void prep_kernel(
    const float* __restrict__ x,
    const float* __restrict__ Wq, const float* __restrict__ Wk,
    const float* __restrict__ Wv, const float* __restrict__ Wo,
    _Float16* __restrict__ x16, _Float16* __restrict__ W16,
    _Float16* __restrict__ WoT, int* __restrict__ ctr)
{
    const int idx = blockIdx.x * 256 + threadIdx.x;
    if (idx == 0) *ctr = 0;
    if (idx < 262144) {
        x16[idx] = (_Float16)x[idx];
    } else if (idx < 262144 + 147456) {
        const int t = idx - 262144;
        const int k = t / 2304, c = t % 2304;        // coalesced read over c
        const int mat = c / 768, cc = c % 768;
        const float* W = (mat == 0) ? Wq : (mat == 1) ? Wk : Wv;
        W16[c * 64 + k] = (_Float16)W[k * 768 + cc];
    } else {
        const int e = idx - 262144 - 147456;         // < 49152
        WoT[(e & 63) * 768 + (e >> 6)] = (_Float16)Wo[e];
    }
}

// ---------------------------------------------------------------------------
// Kernel 1: QKV projection via MFMA. Q output pre-scaled by 1/ln2.
// ---------------------------------------------------------------------------
__global__ __launch_bounds__(256) void qkv_kernel(
    const _Float16* __restrict__ x16, const _Float16* __restrict__ W16,
    const float* __restrict__ bq, const float* __restrict__ bk,
    const float* __restrict__ bv,
    _Float16* __restrict__ Q16, _Float16* __restrict__ K16,
    unsigned short* __restrict__ VT)
{
    const int r0  = blockIdx.x * 64;
    const int c0g = blockIdx.y * 64;
    const int mat = c0g / 768, cc0 = c0g % 768;
    const int h   = cc0 >> 6;
    const int b   = r0 >> 11, s0 = r0 & 2047;

    const int wave = threadIdx.x >> 6, lane = threadIdx.x & 63;
    const int llow = lane & 15, quad = lane >> 4;
    const int rowbase = r0 + 16 * wave;

    const float* bias = (mat == 0) ? bq : (mat == 1) ? bk : bv;

    v8h a0 = *(const v8h*)(x16 + (size_t)(rowbase + llow) * 64 + quad * 8);
    v8h a1 = *(const v8h*)(x16 + (size_t)(rowbase + llow) * 64 + 32 + quad * 8);

    v4f acc[4];
    float bv4[4];
#pragma unroll
    for (int nb = 0; nb < 4; nb++) {
        const int col = c0g + 16 * nb + llow;
        v8h b0 = *(const v8h*)(W16 + (size_t)col * 64 + quad * 8);
        v8h b1 = *(const v8h*)(W16 + (size_t)col * 64 + 32 + quad * 8);
        v4f a = (v4f){0.f, 0.f, 0.f, 0.f};
        a = __builtin_amdgcn_mfma_f32_16x16x32_f16(a0, b0, a, 0, 0, 0);
        a = __builtin_amdgcn_mfma_f32_16x16x32_f16(a1, b1, a, 0, 0, 0);
        acc[nb] = a;
        bv4[nb] = bias[cc0 + 16 * nb + llow];
    }

    const int bh = b * HH + h;
    if (mat == 0) {                                  // Q: pre-scale by 1/ln2
#pragma unroll
        for (int nb = 0; nb < 4; nb++)
#pragma unroll
            for (int r = 0; r < 4; r++) {
                const int s = s0 + 16 * wave + quad * 4 + r;
                Q16[((size_t)bh * SS + s) * 64 + 16 * nb + llow] =
                    (_Float16)((acc[nb][r] + bv4[nb]) * 1.4426950408889634f);
            }
    } else if (mat == 1) {
#pragma unroll
        for (int nb = 0; nb < 4; nb++)
#pragma unroll
            for (int r = 0; r < 4; r++) {
                const int s = s0 + 16 * wave + quad * 4 + r;
                K16[((size_t)bh * SS + s) * 64 + 16 * nb + llow] =
                    (_Float16)(acc[nb][r] + bv4[nb]);
            }
    } else {
#pragma unroll
        for (int nb = 0; nb < 4; nb++) {
            const int d = 16 * nb + llow;
            const int s = s0 + 16 * wave + quad * 4;     // 4 consecutive s
            unsigned short p0 = f2bf(acc[nb][0] + bv4[nb]);
            unsigned short p1 = f2bf(acc[nb][1] + bv4[nb]);
            unsigned short p2 = f2bf(acc[nb][2] + bv4[nb]);
            unsigned short p3 = f2bf(acc[nb][3] + bv4[nb]);
            v2u pk = (v2u){(unsigned)p0 | ((unsigned)p1 << 16),
                           (unsigned)p2 | ((unsigned)p3 << 16)};
            *(v2u*)&VT[((size_t)bh * 64 + d) * SS + s] = pk;
        }
    }
}

// ---------------------------------------------------------------------------
// Kernel 2: persistent work-stealing MFMA flash attention.
// 1024 blocks (4/CU) loop over items from a global atomic counter; item n ->
// (qtile = 63 - n/24, bh = n%24) = LPT (longest-first) order. No dependence
// on block->CU dispatch mapping (R9/R10 static swizzles both failed because
// the round-robin model is wrong). Inner body = R9-verified: S^T form,
// fixed-C exp2 softmax, key-split waves, LDS dbuf DMA staging, diagonal-only
// causal mask.
// ---------------------------------------------------------------------------
__global__ __launch_bounds__(256, 4) void attn_kernel(
    const _Float16* __restrict__ Q16, const _Float16* __restrict__ K16,
    const unsigned short* __restrict__ VTg, _Float16* __restrict__ O16,
    int* __restrict__ ctr)
{
    __shared__ __align__(16) _Float16       Kl[2][64 * 64];   // [key][d], xor-swizzled
    __shared__ __align__(16) unsigned short Vl[2][64 * 64];   // [d][key], xor-swizzled
    __shared__ __align__(16) unsigned short Pl[4][16 * 44];   // [row][key-in-half], stride 44
    __shared__ int s_item;

    const int wave  = threadIdx.x >> 6;
    const int lane  = threadIdx.x & 63;
    const int llow  = lane & 15;
    const int quad  = lane >> 4;
    const int rowg  = wave & 1;
    const int keyh  = wave >> 1;
    const int sw    = llow & 7;

    for (;;) {
        if (threadIdx.x == 0) s_item = atomicAdd(ctr, 1);
        __syncthreads();
        const int n = s_item;
        if (n >= NITEMS) break;

        const int qtile = 63 - n / 24;        // longest items first (LPT)
        const int bh    = n % 24;
        const int qBase = qtile * 32;
        const int q0    = qBase + rowg * 16;

        const _Float16*       Kp = K16 + (size_t)bh * SS * 64;
        const unsigned short* Vp = VTg + (size_t)bh * 64 * SS;

        const _Float16* Qp = Q16 + ((size_t)bh * SS + q0) * 64;
        v8h qa0 = *(const v8h*)(Qp + llow * 64 + quad * 8);
        v8h qa1 = *(const v8h*)(Qp + llow * 64 + 32 + quad * 8);

        v4f o[4];
        float lacc = 0.f;
#pragma unroll
        for (int nb = 0; nb < 4; nb++) o[nb] = (v4f){0.f, 0.f, 0.f, 0.f};

        const int nt = qtile / 2 + 1;   // keys <= 32*qtile+31
        const int qrow = q0 + llow;

        // prefetch tile 0 into buf 0 (wave-uniform base + lane*16 dest)
#pragma unroll
        for (int rep = 0; rep < 2; rep++) {
            int c = rep * 256 + threadIdx.x;
            int row = c >> 3, g = (c & 7) ^ (row & 7);
            async16(Kp + (size_t)row * 64 + g * 8, &Kl[0][(rep * 256 + wave * 64) * 8]);
            async16(Vp + (size_t)row * SS + g * 8, &Vl[0][(rep * 256 + wave * 64) * 8]);
        }

        auto tile_body = [&](int t, auto masked_c) {
            constexpr bool MASKED = decltype(masked_c)::value;
            __syncthreads();                 // drains this tile's DMA
            if (t + 1 < nt) {                // prefetch AFTER barrier -> overlaps compute
                const int ktn = (t + 1) * 64, bufn = (t + 1) & 1;
#pragma unroll
                for (int rep = 0; rep < 2; rep++) {
                    int c = rep * 256 + threadIdx.x;
                    int row = c >> 3, g = (c & 7) ^ (row & 7);
                    async16(Kp + (size_t)(ktn + row) * 64 + g * 8,
                            &Kl[bufn][(rep * 256 + wave * 64) * 8]);
                    async16(Vp + (size_t)row * SS + ktn + g * 8,
                            &Vl[bufn][(rep * 256 + wave * 64) * 8]);
                }
            }
            const int buf = t & 1, kt = t * 64;

            // ---- S^T = K·Q^T over this wave's 32-key half ----
            v4f sc[2];
#pragma unroll
            for (int cb = 0; cb < 2; cb++) {
                const int rk = 32 * keyh + 16 * cb + llow;           // rk&7 == sw
                v8h k0 = *(const v8h*)&Kl[buf][rk * 64 + ((quad ^ sw)) * 8];
                v8h k1 = *(const v8h*)&Kl[buf][rk * 64 + (((4 + quad) ^ sw)) * 8];
                v4f a = (v4f){0.f, 0.f, 0.f, 0.f};
                a = __builtin_amdgcn_mfma_f32_16x16x32_f16(k0, qa0, a, 0, 0, 0);
                a = __builtin_amdgcn_mfma_f32_16x16x32_f16(k1, qa1, a, 0, 0, 0);
                sc[cb] = a;   // C: col=llow=q-row, row=quad*4+r=key offset
            }

            // ---- quirky mask + exp2; pack P directly in A-order ----
#pragma unroll
            for (int cb = 0; cb < 2; cb++) {
                const int kbase = kt + 32 * keyh + 16 * cb + quad * 4;
                unsigned dw[2];
#pragma unroll
                for (int h2 = 0; h2 < 2; h2++) {
                    unsigned lo = 0, hi = 0;
#pragma unroll
                    for (int j2 = 0; j2 < 2; j2++) {
                        const int r = h2 * 2 + j2;
                        const float sv = sc[cb][r];
                        const float e  = __builtin_amdgcn_exp2f(sv - C2FIX);
                        float p;
                        if constexpr (MASKED)
                            p = (kbase + r <= qrow && sv != 0.f) ? e : 0.f;
                        else
                            p = (sv != 0.f) ? e : 0.f;   // tril-zero quirk only
                        lacc += p;
                        if (j2 == 0) lo = __float_as_uint(p);
                        else         hi = __float_as_uint(p);
                    }
                    dw[h2] = (lo >> 16) | (hi & 0xFFFF0000u);   // bf16-trunc pair
                }
                *(v2u*)&Pl[wave][llow * 44 + 16 * cb + 4 * quad] = (v2u){dw[0], dw[1]};
            }

            // ---- P A-frag: single b128, same wave -> lgkm only ----
            v8s pa = *(const v8s*)&Pl[wave][llow * 44 + quad * 8];

            // ---- PV over the 32-key half (bf16): A=P, B=V^T ----
#pragma unroll
            for (int nb = 0; nb < 4; nb++) {
                const int rv = 16 * nb + llow;                       // rv&7 == sw
                v8s vv = *(const v8s*)&Vl[buf][rv * 64 + (((4 * keyh + quad) ^ sw)) * 8];
                o[nb] = __builtin_amdgcn_mfma_f32_16x16x32_bf16(pa, vv, o[nb], 0, 0, 0);
            }
        };

        for (int t = 0; t < nt - 1; t++) tile_body(t, std::false_type{});
        tile_body(nt - 1, std::true_type{});            // diagonal tile: causal mask

        // ---- epilogue ----
        lacc += __shfl_xor(lacc, 16);
        lacc += __shfl_xor(lacc, 32);   // row llow's half-sum in all quads

        __syncthreads();                                  // last tile's LDS reads done
        float* redO = (float*)&Kl[0][0];                  // [32 rows][stride 68]
        float* redL = (float*)&Vl[0][0];                  // [32 rows]
        if (keyh == 1) {
#pragma unroll
            for (int nb = 0; nb < 4; nb++)
#pragma unroll
                for (int r = 0; r < 4; r++)
                    redO[(rowg * 16 + quad * 4 + r) * 68 + 16 * nb + llow] = o[nb][r];
            if (lane < 16)
                redL[rowg * 16 + lane] = lacc;            // row q0+lane half-sum
        }
        __syncthreads();
        if (keyh == 0) {
            float lr[4];
#pragma unroll
            for (int r = 0; r < 4; r++)
                lr[r] = __shfl(lacc, quad * 4 + r) + redL[rowg * 16 + quad * 4 + r];
            _Float16* Op = O16 + ((size_t)bh * SS + q0) * 64;
#pragma unroll
            for (int nb = 0; nb < 4; nb++)
#pragma unroll
                for (int r = 0; r < 4; r++) {
                    float v = o[nb][r] + redO[(rowg * 16 + quad * 4 + r) * 68 + 16 * nb + llow];
                    Op[(quad * 4 + r) * 64 + 16 * nb + llow] = (_Float16)(v / lr[r]);
                }
        }
        // loop-top __syncthreads (after next item broadcast) orders the
        // epilogue's LDS reads before the next item's DMA overwrites Kl/Vl.
    }
}

// ---------------------------------------------------------------------------
// Kernel 3: output projection via MFMA (unchanged).
// ---------------------------------------------------------------------------
__global__ __launch_bounds__(256) void out_kernel(
    const _Float16* __restrict__ O16, const _Float16* __restrict__ WoT,
    const float* __restrict__ bo, float* __restrict__ out)
{
    __shared__ __align__(16) float red[4][16][66];
    const int r0   = blockIdx.x * 16;
    const int wave = threadIdx.x >> 6, lane = threadIdx.x & 63;
    const int llow = lane & 15, quad = lane >> 4;
    const int b = r0 >> 11, s = r0 & 2047;

    v4f acc[4];
#pragma unroll
    for (int cb = 0; cb < 4; cb++) acc[cb] = (v4f){0.f, 0.f, 0.f, 0.f};

#pragma unroll
    for (int i = 0; i < 6; i++) {
        const int kb = wave * 6 + i;                // 0..23
        const int h = kb >> 1, dseg = (kb & 1) * 32;
        v8h af = *(const v8h*)(O16 + ((size_t)(b * HH + h) * SS + s + llow) * 64 + dseg + quad * 8);
#pragma unroll
        for (int cb = 0; cb < 4; cb++) {
            v8h bf = *(const v8h*)(WoT + (size_t)(16 * cb + llow) * 768 + kb * 32 + quad * 8);
            acc[cb] = __builtin_amdgcn_mfma_f32_16x16x32_f16(af, bf, acc[cb], 0, 0, 0);
        }
    }

#pragma unroll
    for (int cb = 0; cb < 4; cb++)
#pragma unroll
        for (int r = 0; r < 4; r++)
            red[wave][quad * 4 + r][16 * cb + llow] = acc[cb][r];
    __syncthreads();

    const int col = threadIdx.x & 63, rr = threadIdx.x >> 6;
    const float bias = bo[col];
    for (int i = rr; i < 16; i += 4) {
        float sum = red[0][i][col] + red[1][i][col] + red[2][i][col] + red[3][i][col] + bias;
        out[(size_t)(r0 + i) * 64 + col] = sum;
    }
}

// ---------------------------------------------------------------------------
extern "C" void kernel_launch(void* const* d_in, const int* in_sizes, int n_in,
                              void* d_out, int out_size, void* d_ws, size_t ws_size,
                              hipStream_t stream)
{
    const float* x  = (const float*)d_in[0];
    const float* Wq = (const float*)d_in[1];
    const float* bq = (const float*)d_in[2];
    const float* Wk = (const float*)d_in[3];
    const float* bk = (const float*)d_in[4];
    const float* Wv = (const float*)d_in[5];
    const float* bv = (const float*)d_in[6];
    const float* Wo = (const float*)d_in[7];
    const float* bo = (const float*)d_in[8];
    float* out = (float*)d_out;

    char* w = (char*)d_ws;
    const size_t MB = 1024 * 1024;
    _Float16*       x16 = (_Float16*)(w);                 // 512 KB
    _Float16*       W16 = (_Float16*)(w + 512 * 1024);    // 288 KB
    _Float16*       WoT = (_Float16*)(w + 832 * 1024);    // 96 KB
    _Float16*       Q16 = (_Float16*)(w + 1 * MB);        // 6 MB each
    _Float16*       K16 = (_Float16*)(w + 7 * MB);
    unsigned short* VT  = (unsigned short*)(w + 13 * MB);
    _Float16*       O16 = (_Float16*)(w + 19 * MB);
    int*            ctr = (int*)(w + 25 * MB);

    prep_kernel<<<1792, 256, 0, stream>>>(x, Wq, Wk, Wv, Wo, x16, W16, WoT, ctr);
    qkv_kernel<<<dim3(64, 36), 256, 0, stream>>>(x16, W16, bq, bk, bv, Q16, K16, VT);
    attn_kernel<<<1024, 256, 0, stream>>>(Q16, K16, VT, O16, ctr);
    out_kernel<<<(BB * SS) / 16, 256, 0, stream>>>(O16, WoT, bo, out);
}

// Round 12
// 133.050 us; speedup vs baseline: 1.0941x; 1.0941x over previous
//
#include <hip/hip_runtime.h>
#include <math.h>
#include <type_traits>

#define BB 2
#define SS 2048
#define DD 64
#define HH 12
// Q pre-scaled by 1/ln2 in qkv; exp(s-16) == exp2(s' - 16/ln2)
#define C2FIX 23.083120654223414f

typedef _Float16 v8h __attribute__((ext_vector_type(8)));
typedef short    v8s __attribute__((ext_vector_type(8)));
typedef float    v4f __attribute__((ext_vector_type(4)));
typedef unsigned int v2u __attribute__((ext_vector_type(2)));

__device__ __forceinline__ unsigned short f2bf(float f) {
    unsigned u = __float_as_uint(f);
    u += 0x7FFF + ((u >> 16) & 1);          // RTN-even
    return (unsigned short)(u >> 16);
}

__device__ __forceinline__ void async16(const void* g, void* l) {
    __builtin_amdgcn_global_load_lds(
        (const __attribute__((address_space(1))) unsigned int*)g,
        (__attribute__((address_space(3))) unsigned int*)l, 16, 0, 0);
}

// ---------------------------------------------------------------------------
// Kernel 0: prep. x -> x16 fp16; [Wq|Wk|Wv] -> W16 fp16 B-layout [2304][64];
// Wo -> WoT fp16 [64][768].
// ---------------------------------------------------------------------------
__global__ __launch_bounds__(256) void prep_kernel(
    const float* __restrict__ x,
    const float* __restrict__ Wq, const float* __restrict__ Wk,
    const float* __restrict__ Wv, const float* __restrict__ Wo,
    _Float16* __restrict__ x16, _Float16* __restrict__ W16,
    _Float16* __restrict__ WoT)
{
    const int idx = blockIdx.x * 256 + threadIdx.x;
    if (idx < 262144) {
        x16[idx] = (_Float16)x[idx];
    } else if (idx < 262144 + 147456) {
        const int t = idx - 262144;
        const int k = t / 2304, c = t % 2304;        // coalesced read over c
        const int mat = c / 768, cc = c % 768;
        const float* W = (mat == 0) ? Wq : (mat == 1) ? Wk : Wv;
        W16[c * 64 + k] = (_Float16)W[k * 768 + cc];
    } else {
        const int e = idx - 262144 - 147456;         // < 49152
        WoT[(e & 63) * 768 + (e >> 6)] = (_Float16)Wo[e];
    }
}

// ---------------------------------------------------------------------------
// Kernel 1: QKV projection via MFMA. Q output pre-scaled by 1/ln2.
// ---------------------------------------------------------------------------
__global__ __launch_bounds__(256) void qkv_kernel(
    const _Float16* __restrict__ x16, const _Float16* __restrict__ W16,
    const float* __restrict__ bq, const float* __restrict__ bk,
    const float* __restrict__ bv,
    _Float16* __restrict__ Q16, _Float16* __restrict__ K16,
    unsigned short* __restrict__ VT)
{
    const int r0  = blockIdx.x * 64;
    const int c0g = blockIdx.y * 64;
    const int mat = c0g / 768, cc0 = c0g % 768;
    const int h   = cc0 >> 6;
    const int b   = r0 >> 11, s0 = r0 & 2047;

    const int wave = threadIdx.x >> 6, lane = threadIdx.x & 63;
    const int llow = lane & 15, quad = lane >> 4;
    const int rowbase = r0 + 16 * wave;

    const float* bias = (mat == 0) ? bq : (mat == 1) ? bk : bv;

    v8h a0 = *(const v8h*)(x16 + (size_t)(rowbase + llow) * 64 + quad * 8);
    v8h a1 = *(const v8h*)(x16 + (size_t)(rowbase + llow) * 64 + 32 + quad * 8);

    v4f acc[4];
    float bv4[4];
#pragma unroll
    for (int nb = 0; nb < 4; nb++) {
        const int col = c0g + 16 * nb + llow;
        v8h b0 = *(const v8h*)(W16 + (size_t)col * 64 + quad * 8);
        v8h b1 = *(const v8h*)(W16 + (size_t)col * 64 + 32 + quad * 8);
        v4f a = (v4f){0.f, 0.f, 0.f, 0.f};
        a = __builtin_amdgcn_mfma_f32_16x16x32_f16(a0, b0, a, 0, 0, 0);
        a = __builtin_amdgcn_mfma_f32_16x16x32_f16(a1, b1, a, 0, 0, 0);
        acc[nb] = a;
        bv4[nb] = bias[cc0 + 16 * nb + llow];
    }

    const int bh = b * HH + h;
    if (mat == 0) {                                  // Q: pre-scale by 1/ln2
#pragma unroll
        for (int nb = 0; nb < 4; nb++)
#pragma unroll
            for (int r = 0; r < 4; r++) {
                const int s = s0 + 16 * wave + quad * 4 + r;
                Q16[((size_t)bh * SS + s) * 64 + 16 * nb + llow] =
                    (_Float16)((acc[nb][r] + bv4[nb]) * 1.4426950408889634f);
            }
    } else if (mat == 1) {
#pragma unroll
        for (int nb = 0; nb < 4; nb++)
#pragma unroll
            for (int r = 0; r < 4; r++) {
                const int s = s0 + 16 * wave + quad * 4 + r;
                K16[((size_t)bh * SS + s) * 64 + 16 * nb + llow] =
                    (_Float16)(acc[nb][r] + bv4[nb]);
            }
    } else {
#pragma unroll
        for (int nb = 0; nb < 4; nb++) {
            const int d = 16 * nb + llow;
            const int s = s0 + 16 * wave + quad * 4;     // 4 consecutive s
            unsigned short p0 = f2bf(acc[nb][0] + bv4[nb]);
            unsigned short p1 = f2bf(acc[nb][1] + bv4[nb]);
            unsigned short p2 = f2bf(acc[nb][2] + bv4[nb]);
            unsigned short p3 = f2bf(acc[nb][3] + bv4[nb]);
            v2u pk = (v2u){(unsigned)p0 | ((unsigned)p1 << 16),
                           (unsigned)p2 | ((unsigned)p3 << 16)};
            *(v2u*)&VT[((size_t)bh * 64 + d) * SS + s] = pk;
        }
    }
}

// ---------------------------------------------------------------------------
// Kernel 2: MFMA flash attention, R12: 64 q-rows/block, NO key-split —
// each of 4 waves owns 16 rows x full 64-key tile (16 MFMA/wave/tile,
// 2x R9). Staged-tile count halves at same total MFMA work -> per-tile
// fixed overhead (barrier, vmcnt drain, chain startup) amortized 2x.
// Epilogue needs no LDS merge (full row sums in-wave). Pl stride 64 with
// octet XOR swizzle (octet^(llow&7)): b64 writes and b128 reads both
// <=2-way (free). LDS = 40960 B exactly -> 4 blocks/CU.
// S^T form, exp2 fixed-C softmax, diagonal-only mask (R9-verified).
// ---------------------------------------------------------------------------
__global__ __launch_bounds__(256, 4) void attn_kernel(
    const _Float16* __restrict__ Q16, const _Float16* __restrict__ K16,
    const unsigned short* __restrict__ VTg, _Float16* __restrict__ O16)
{
    __shared__ __align__(16) _Float16       Kl[2][64 * 64];   // [key][d], xor-swizzled
    __shared__ __align__(16) unsigned short Vl[2][64 * 64];   // [d][key], xor-swizzled
    __shared__ __align__(16) unsigned short Pl[4][16 * 64];   // [row][key], octet-swizzled

    const int bh    = blockIdx.y;
    const int qtile = (int)((blockIdx.x + 11 * blockIdx.y) & 31);   // balance swizzle
    const int qBase = qtile * 64;
    const int wave  = threadIdx.x >> 6;
    const int lane  = threadIdx.x & 63;
    const int llow  = lane & 15;
    const int quad  = lane >> 4;
    const int q0    = qBase + 16 * wave;

    const _Float16*       Kp = K16 + (size_t)bh * SS * 64;
    const unsigned short* Vp = VTg + (size_t)bh * 64 * SS;

    const _Float16* Qp = Q16 + ((size_t)bh * SS + q0) * 64;
    v8h qa0 = *(const v8h*)(Qp + llow * 64 + quad * 8);
    v8h qa1 = *(const v8h*)(Qp + llow * 64 + 32 + quad * 8);

    v4f o[4];
    float lacc = 0.f;
#pragma unroll
    for (int nb = 0; nb < 4; nb++) o[nb] = (v4f){0.f, 0.f, 0.f, 0.f};

    const int nt = qtile + 1;       // 64-key tiles needed
    const int qrow = q0 + llow;
    const int sw = llow & 7;

    // prefetch tile 0 into buf 0 (wave-uniform base + lane*16 dest, DMA rule)
#pragma unroll
    for (int rep = 0; rep < 2; rep++) {
        int c = rep * 256 + threadIdx.x;
        int row = c >> 3, g = (c & 7) ^ (row & 7);
        async16(Kp + (size_t)row * 64 + g * 8, &Kl[0][(rep * 256 + wave * 64) * 8]);
        async16(Vp + (size_t)row * SS + g * 8, &Vl[0][(rep * 256 + wave * 64) * 8]);
    }

    auto tile_body = [&](int t, auto masked_c) {
        constexpr bool MASKED = decltype(masked_c)::value;
        __syncthreads();                 // drains this tile's DMA
        if (t + 1 < nt) {                // prefetch AFTER barrier -> overlaps compute
            const int ktn = (t + 1) * 64, bufn = (t + 1) & 1;
#pragma unroll
            for (int rep = 0; rep < 2; rep++) {
                int c = rep * 256 + threadIdx.x;
                int row = c >> 3, g = (c & 7) ^ (row & 7);
                async16(Kp + (size_t)(ktn + row) * 64 + g * 8,
                        &Kl[bufn][(rep * 256 + wave * 64) * 8]);
                async16(Vp + (size_t)row * SS + ktn + g * 8,
                        &Vl[bufn][(rep * 256 + wave * 64) * 8]);
            }
        }
        const int buf = t & 1, kt = t * 64;

        // ---- S^T = K·Q^T over all 64 keys: 4 col-blocks of 16 ----
        v4f sc[4];
#pragma unroll
        for (int cb = 0; cb < 4; cb++) {
            const int rk = 16 * cb + llow;                       // rk&7 == sw
            v8h k0 = *(const v8h*)&Kl[buf][rk * 64 + ((quad ^ sw)) * 8];
            v8h k1 = *(const v8h*)&Kl[buf][rk * 64 + (((4 + quad) ^ sw)) * 8];
            v4f a = (v4f){0.f, 0.f, 0.f, 0.f};
            a = __builtin_amdgcn_mfma_f32_16x16x32_f16(k0, qa0, a, 0, 0, 0);
            a = __builtin_amdgcn_mfma_f32_16x16x32_f16(k1, qa1, a, 0, 0, 0);
            sc[cb] = a;   // C: col=llow=q-row, row=quad*4+r=key offset
        }

        // ---- quirky mask + exp2; pack P in A-order, octet-swizzled ----
#pragma unroll
        for (int cb = 0; cb < 4; cb++) {
            const int kbase = kt + 16 * cb + quad * 4;
            unsigned dw[2];
#pragma unroll
            for (int h2 = 0; h2 < 2; h2++) {
                unsigned lo = 0, hi = 0;
#pragma unroll
                for (int j2 = 0; j2 < 2; j2++) {
                    const int r = h2 * 2 + j2;
                    const float sv = sc[cb][r];
                    const float e  = __builtin_amdgcn_exp2f(sv - C2FIX);
                    float p;
                    if constexpr (MASKED)
                        p = (kbase + r <= qrow && sv != 0.f) ? e : 0.f;
                    else
                        p = (sv != 0.f) ? e : 0.f;   // tril-zero quirk only
                    lacc += p;
                    if (j2 == 0) lo = __float_as_uint(p);
                    else         hi = __float_as_uint(p);
                }
                dw[h2] = (lo >> 16) | (hi & 0xFFFF0000u);   // bf16-trunc pair
            }
            // natural pos 16cb+4quad -> octet (2cb+(quad>>1)) ^ sw, half (quad&1)*4
            *(v2u*)&Pl[wave][llow * 64 + (((2 * cb + (quad >> 1)) ^ sw) * 8)
                             + (quad & 1) * 4] = (v2u){dw[0], dw[1]};
        }

        // ---- P A-frags: 2x b128, octet-swizzled (same wave: lgkm only) ----
        v8s pa0 = *(const v8s*)&Pl[wave][llow * 64 + ((quad ^ sw) * 8)];
        v8s pa1 = *(const v8s*)&Pl[wave][llow * 64 + (((4 + quad) ^ sw) * 8)];

        // ---- PV over all 64 keys (bf16): A=P, B=V^T ----
#pragma unroll
        for (int nb = 0; nb < 4; nb++) {
            const int rv = 16 * nb + llow;                       // rv&7 == sw
            v8s vv0 = *(const v8s*)&Vl[buf][rv * 64 + ((quad ^ sw)) * 8];
            v8s vv1 = *(const v8s*)&Vl[buf][rv * 64 + (((4 + quad) ^ sw)) * 8];
            o[nb] = __builtin_amdgcn_mfma_f32_16x16x32_bf16(pa0, vv0, o[nb], 0, 0, 0);
            o[nb] = __builtin_amdgcn_mfma_f32_16x16x32_bf16(pa1, vv1, o[nb], 0, 0, 0);
        }
    };

    for (int t = 0; t < nt - 1; t++) tile_body(t, std::false_type{});
    tile_body(nt - 1, std::true_type{});            // diagonal tile: causal mask

    // ---- epilogue: full row sums already in-wave; no LDS merge ----
    lacc += __shfl_xor(lacc, 16);
    lacc += __shfl_xor(lacc, 32);   // all quads: row llow's full sum
    float lr[4];
#pragma unroll
    for (int r = 0; r < 4; r++)
        lr[r] = __shfl(lacc, quad * 4 + r);         // sum for row quad*4+r
    _Float16* Op = O16 + ((size_t)bh * SS + q0) * 64;
#pragma unroll
    for (int nb = 0; nb < 4; nb++)
#pragma unroll
        for (int r = 0; r < 4; r++)
            Op[(quad * 4 + r) * 64 + 16 * nb + llow] = (_Float16)(o[nb][r] / lr[r]);
}

// ---------------------------------------------------------------------------
// Kernel 3: output projection via MFMA (unchanged).
// ---------------------------------------------------------------------------
__global__ __launch_bounds__(256) void out_kernel(
    const _Float16* __restrict__ O16, const _Float16* __restrict__ WoT,
    const float* __restrict__ bo, float* __restrict__ out)
{
    __shared__ __align__(16) float red[4][16][66];
    const int r0   = blockIdx.x * 16;
    const int wave = threadIdx.x >> 6, lane = threadIdx.x & 63;
    const int llow = lane & 15, quad = lane >> 4;
    const int b = r0 >> 11, s = r0 & 2047;

    v4f acc[4];
#pragma unroll
    for (int cb = 0; cb < 4; cb++) acc[cb] = (v4f){0.f, 0.f, 0.f, 0.f};

#pragma unroll
    for (int i = 0; i < 6; i++) {
        const int kb = wave * 6 + i;                // 0..23
        const int h = kb >> 1, dseg = (kb & 1) * 32;
        v8h af = *(const v8h*)(O16 + ((size_t)(b * HH + h) * SS + s + llow) * 64 + dseg + quad * 8);
#pragma unroll
        for (int cb = 0; cb < 4; cb++) {
            v8h bf = *(const v8h*)(WoT + (size_t)(16 * cb + llow) * 768 + kb * 32 + quad * 8);
            acc[cb] = __builtin_amdgcn_mfma_f32_16x16x32_f16(af, bf, acc[cb], 0, 0, 0);
        }
    }

#pragma unroll
    for (int cb = 0; cb < 4; cb++)
#pragma unroll
        for (int r = 0; r < 4; r++)
            red[wave][quad * 4 + r][16 * cb + llow] = acc[cb][r];
    __syncthreads();

    const int col = threadIdx.x & 63, rr = threadIdx.x >> 6;
    const float bias = bo[col];
    for (int i = rr; i < 16; i += 4) {
        float sum = red[0][i][col] + red[1][i][col] + red[2][i][col] + red[3][i][col] + bias;
        out[(size_t)(r0 + i) * 64 + col] = sum;
    }
}

// ---------------------------------------------------------------------------
extern "C" void kernel_launch(void* const* d_in, const int* in_sizes, int n_in,
                              void* d_out, int out_size, void* d_ws, size_t ws_size,
                              hipStream_t stream)
{
    const float* x  = (const float*)d_in[0];
    const float* Wq = (const float*)d_in[1];
    const float* bq = (const float*)d_in[2];
    const float* Wk = (const float*)d_in[3];
    const float* bk = (const float*)d_in[4];
    const float* Wv = (const float*)d_in[5];
    const float* bv = (const float*)d_in[6];
    const float* Wo = (const float*)d_in[7];
    const float* bo = (const float*)d_in[8];
    float* out = (float*)d_out;

    char* w = (char*)d_ws;
    const size_t MB = 1024 * 1024;
    _Float16*       x16 = (_Float16*)(w);                 // 512 KB
    _Float16*       W16 = (_Float16*)(w + 512 * 1024);    // 288 KB
    _Float16*       WoT = (_Float16*)(w + 832 * 1024);    // 96 KB
    _Float16*       Q16 = (_Float16*)(w + 1 * MB);        // 6 MB each
    _Float16*       K16 = (_Float16*)(w + 7 * MB);
    unsigned short* VT  = (unsigned short*)(w + 13 * MB);
    _Float16*       O16 = (_Float16*)(w + 19 * MB);

    prep_kernel<<<1792, 256, 0, stream>>>(x, Wq, Wk, Wv, Wo, x16, W16, WoT);
    qkv_kernel<<<dim3(64, 36), 256, 0, stream>>>(x16, W16, bq, bk, bv, Q16, K16, VT);
    attn_kernel<<<dim3(32, BB * HH), 256, 0, stream>>>(Q16, K16, VT, O16);
    out_kernel<<<(BB * SS) / 16, 256, 0, stream>>>(O16, WoT, bo, out);
}